// Round 4
// baseline (287.807 us; speedup 1.0000x reference)
//
#include <hip/hip_runtime.h>
#include <hip/hip_bf16.h>

// Fused Conv3d(3->16,k=3,valid) + conv_b + ReLU + maxpool2x2x2
// + spatial mean(fp32) + /2 + bias + channel-sum  ->  out[32] fp32.
//
// R13: LDS-read diet — kh=1 tap via cross-lane DPP instead of ds_read.
//  Per kw, the kh=0/kh=2 reads jointly hold all 4 h-chunks across the hh
//  lane split: F0=(h0@hh0,h1@hh1), F2=(h2@hh0,h3@hh1). The kh=1 frag
//  (h1@hh0,h2@hh1) = quad_perm^1(hh ? F0 : F2) — partner lane shares
//  wi/hs/row/buffer-select, so the exchange is layout-exact.
//  ds_read_b128 9 -> 6 per wave-iter (-30% LDS pipe, the dominant pipe).
//  dp unrolled by 2 (t-loop): ^p16 address XORs + buffer selects become
//  precomputed even/odd register sets (rE/rO, wE/wO).
// (R12 kept, verified absmax=0): operand-swapped MFMA (M=spatial,
//  N=(ch,dd)), in-register 2x2 pool + DPP dd-pool, d-plane rotation
//  (stage 2 planes/iter), ci-fast slots, XOR bank swizzle, lgkm-only BAR,
//  XCD-aware bijective block swizzle.
//  MFMA m32n32k16, D: col=lane&31, row=(reg&3)+8*(reg>>2)+4*(lane>>5).

typedef __attribute__((ext_vector_type(8)))  short  short8;
typedef __attribute__((ext_vector_type(2)))  float  floatx2;
typedef __attribute__((ext_vector_type(4)))  float  floatx4;
typedef __attribute__((ext_vector_type(4)))  int    intx4;
typedef __attribute__((ext_vector_type(16))) float  floatx16;

__device__ __forceinline__ short f2bf(float f) {
    unsigned u = __builtin_bit_cast(unsigned, f);
    unsigned r = (u + 0x7FFFu + ((u >> 16) & 1u)) >> 16;
    return (short)r;
}

__device__ __forceinline__ unsigned pkbf2(float a, float b) {
    __hip_bfloat162 h = __float22bfloat162_rn(float2{a, b});  // v_cvt_pk_bf16_f32
    unsigned r;
    __builtin_memcpy(&r, &h, 4);
    return r;
}

template <int CTRL>
__device__ __forceinline__ float dpp_max(float v) {
    int x = __builtin_bit_cast(int, v);
    int y = __builtin_amdgcn_mov_dpp(x, CTRL, 0xF, 0xF, true);
    return fmaxf(v, __builtin_bit_cast(float, y));
}

// F1 = quad_perm^1( hh ? F0 : F2 )  — kh=1 B-frag from kh=0/kh=2 frags.
__device__ __forceinline__ short8 mixF1(short8 f0, short8 f2, bool hh1) {
    intx4 a = __builtin_bit_cast(intx4, f0);
    intx4 b = __builtin_bit_cast(intx4, f2);
    intx4 r;
    #pragma unroll
    for (int i = 0; i < 4; ++i) {
        int s = hh1 ? a[i] : b[i];                              // v_cndmask
        r[i] = __builtin_amdgcn_mov_dpp(s, 0xB1, 0xF, 0xF, true); // lane^1
    }
    return __builtin_bit_cast(short8, r);
}

// LDS-only barrier: drain DS ops, leave global loads in flight (no vmcnt).
#define BAR() asm volatile("s_waitcnt lgkmcnt(0)\n\ts_barrier" ::: "memory")

#define BUFSZ 16640

// ---- init: wtab[f=kh*3+kw][lane][8] zero-padded B-frags + out = bias sums ----
__global__ void init_kernel(const float* __restrict__ wg,
                            const float* __restrict__ biasg,
                            short* __restrict__ wtab,   // d_ws: 9*64*8 bf16 = 9216 B
                            float* __restrict__ out)    // [32]
{
    const int t = threadIdx.x;               // 0..575
    if (t < 576) {
        const int lane = t & 63, f = t >> 6;
        const int kh = f / 3, kw = f % 3;
        const int m = lane & 31, hs = lane >> 5;
        const int ch = m >> 1, dd = m & 1;   // col = 2*ch + dd
        short8 v;
        #pragma unroll
        for (int j = 0; j < 8; ++j) {
            const int s = hs * 8 + j;        // k-slot: dl_rel = s>>2, ci = s&3
            const int dl = s >> 2, ci = s & 3;
            const int kd = dl - dd;
            v[j] = (ci < 3 && kd >= 0 && kd < 3)
                 ? f2bf(wg[ch * 81 + ci * 27 + kd * 9 + kh * 3 + kw]) : (short)0;
        }
        ((short8*)wtab)[f * 64 + lane] = v;
    }
    if (t < 32) {
        float s = 0.f;
        #pragma unroll
        for (int cc = 0; cc < 16; ++cc) s += biasg[cc];
        out[t] = s;   // conv blocks atomicAdd on top
    }
}

__global__ __launch_bounds__(512, 4) void fused_conv_pool_reduce(
    const float* __restrict__ xg,    // f32 [32][3][32][128][128]
    const short* __restrict__ wtab,  // bf16 frag table in d_ws
    const float* __restrict__ cbg,   // f32 [16]
    float* __restrict__ out)         // f32 [32]
{
    __shared__ __align__(16) short rawT[2 * 130 * 64];  // 33,280 B (2 buffers)
    __shared__ float wsums[8];

    // XCD-aware bijective swizzle: 2016 = 8 XCDs x 252 (4 b x 63 hp each).
    const int lin = blockIdx.y * 63 + blockIdx.x;      // 0..2015
    const int nl  = (lin & 7) * 252 + (lin >> 3);
    const int hp  = nl % 63;
    const int b   = nl / 63;

    const int tid = threadIdx.x;  // 0..511
    const int lane = tid & 63;
    const int wv   = tid >> 6;    // wave = 16-wide w tile
    const int hs   = lane >> 5;

    // ---- resident B-frags (36 VGPR), conv-bias, validity masks ----
    short8 af[9];
    #pragma unroll
    for (int f = 0; f < 9; ++f) af[f] = ((const short8*)wtab)[f * 64 + lane];
    const float cbv = cbg[(lane >> 1) & 15];   // ch = (lane&31)>>1
    float maskA[4];
    #pragma unroll
    for (int a = 0; a < 4; ++a) {
        const bool ok = ((lane & 1) == 0) && (wv * 8 + 2 * a + hs <= 62);
        maskA[a] = ok ? 1.0f : 0.0f;
    }
    const bool hh1 = (lane & 1);

    // ---- zero rows 128/129 of both buffers (once) ----
    if (tid < 64)
        *(unsigned long long*)((char*)rawT + (tid >> 5) * BUFSZ + 16384 + (tid & 31) * 8) = 0ULL;

    #define SWZ(r) (((r) ^ ((r) >> 3)) & 7)

    // ---- per-iter stage map: 2 planes (pair), 2 rows x 8B per thread ----
    const int w4 = tid & 31, dr2 = (tid >> 5) & 1, rr = (tid >> 6) & 1, hr2 = (tid >> 7) & 3;
    int wE[2], wO[2];
    #pragma unroll
    for (int j = 0; j < 2; ++j) {
        const int row = 2 * w4 + 64 * rr + j;
        wE[j] = row * 128 + ((hr2 * 2) ^ SWZ(row)) * 16 + dr2 * 8;
        wO[j] = wE[j] ^ 16;
    }

    // ---- read maps: kh=0 and kh=2 taps only (kh=1 via DPP), even/odd dp ----
    const int wi = (lane >> 1) & 15;
    int rE[2][3], rO[2][3];
    #pragma unroll
    for (int i = 0; i < 2; ++i) {        // i=0 -> kh=0, i=1 -> kh=2
        #pragma unroll
        for (int kw = 0; kw < 3; ++kw) {
            const int row = wv * 16 + wi + kw;
            const int phys = (((int)hh1 + 2 * i) * 2 + hs) ^ SWZ(row);
            rE[i][kw] = row * 128 + phys * 16;
            rO[i][kw] = rE[i][kw] ^ 16;
        }
    }

    // ---- prologue: stage pairs 0,1 (planes 0..3) into buffer 0 ----
    {
        const int w4p = tid & 31, drp = (tid >> 5) & 3, hrp = (tid >> 7) & 3;
        const float* srcP = xg + ((size_t)b * 96 + drp) * 16384 + (2 * hp + hrp) * 128 + 4 * w4p;
        const floatx4 c0 = *(const floatx4*)(srcP);
        const floatx4 c1 = *(const floatx4*)(srcP + 524288);
        const floatx4 c2 = *(const floatx4*)(srcP + 1048576);
        const int chunkL = hrp * 2 + (drp >> 1);
        #pragma unroll
        for (int i = 0; i < 4; ++i) {
            const int row = 4 * w4p + i;
            const int ad = row * 128 + (chunkL ^ SWZ(row)) * 16 + (drp & 1) * 8;
            uint2 pk;
            pk.x = pkbf2(c0[i], c1[i]);
            pk.y = pkbf2(c2[i], 0.0f);
            *(uint2*)((char*)rawT + ad) = pk;
        }
    }

    // ---- prologue prefetch: pair 2 (planes 4,5), float2 per ci ----
    const float* src2 = xg + ((size_t)b * 96 + 4 + dr2) * 16384
                      + (2 * hp + hr2) * 128 + 2 * w4 + 64 * rr;
    floatx2 A0 = *(const floatx2*)(src2);
    floatx2 A1 = *(const floatx2*)(src2 + 524288);
    floatx2 A2 = *(const floatx2*)(src2 + 1048576);

    float vsum = 0.f;

    auto stageA = [&](int bw, const int (&wa)[2]) {
        uint2 pk0, pk1;
        pk0.x = pkbf2(A0[0], A1[0]); pk0.y = pkbf2(A2[0], 0.0f);
        pk1.x = pkbf2(A0[1], A1[1]); pk1.y = pkbf2(A2[1], 0.0f);
        *(uint2*)((char*)rawT + bw + wa[0]) = pk0;
        *(uint2*)((char*)rawT + bw + wa[1]) = pk1;
    };
    auto loadA = [&]() {
        src2 += 32768;
        A0 = *(const floatx2*)(src2);
        A1 = *(const floatx2*)(src2 + 524288);
        A2 = *(const floatx2*)(src2 + 1048576);
    };
    auto compute = [&](int roff, const int (&ra)[2][3]) {
        floatx16 acc = {0.f,0.f,0.f,0.f,0.f,0.f,0.f,0.f,
                        0.f,0.f,0.f,0.f,0.f,0.f,0.f,0.f};
        #pragma unroll
        for (int kw = 0; kw < 3; ++kw) {
            const short8 f0 = *(const short8*)((char*)rawT + roff + ra[0][kw]);
            const short8 f2 = *(const short8*)((char*)rawT + roff + ra[1][kw]);
            const short8 f1 = mixF1(f0, f2, hh1);
            acc = __builtin_amdgcn_mfma_f32_32x32x16_bf16(f0, af[kw],     acc, 0, 0, 0);
            acc = __builtin_amdgcn_mfma_f32_32x32x16_bf16(f1, af[3 + kw], acc, 0, 0, 0);
            acc = __builtin_amdgcn_mfma_f32_32x32x16_bf16(f2, af[6 + kw], acc, 0, 0, 0);
        }
        // epilogue: acc[4a..4a+3] = one 2x2 h/w window (in-reg max),
        // dd-pool = DPP ^1, then +cb, relu, masked accumulate.
        #pragma unroll
        for (int a = 0; a < 4; ++a) {
            float m01 = fmaxf(acc[4 * a],     acc[4 * a + 1]);
            float m23 = fmaxf(acc[4 * a + 2], acc[4 * a + 3]);
            float m   = fmaxf(m01, m23);
            m = dpp_max<0xB1>(m);                 // pool over dd (lane ^ 1)
            const float v = fmaxf(m + cbv, 0.f);  // +conv_b, relu (post-pool)
            vsum = fmaf(maskA[a], v, vsum);
        }
    };

    // ---- main loop: dp = 2t, 2t+1 for t=0..6, tail dp=14 ----
    for (int t = 0; t < 7; ++t) {
        const int bufA = (t & 1) ? BUFSZ : 0;   // read buffer, even dp
        const int bufB = BUFSZ - bufA;          // stage buffer (both sub-iters)
        // even dp = 2t: stage pair 2t+2, prefetch pair 2t+3
        stageA(bufB, wE);
        loadA();
        BAR();
        compute(bufA, rE);
        // odd dp = 2t+1: stage pair 2t+3, prefetch pair 2t+4
        stageA(bufB, wO);
        if (t < 6) loadA();
        BAR();
        compute(hs ? bufB : bufA, rO);          // hs-split buffer (rotation)
    }
    // tail dp = 14 (even parity, pairs 14,15 already staged & visible)
    compute(BUFSZ, rE);

    // mask already zeroes invalid lanes/groups: plain full-wave sum
    float s = vsum;
    #pragma unroll
    for (int off = 1; off < 64; off <<= 1) s += __shfl_xor(s, off, 64);

    if (lane == 0) wsums[wv] = s;
    __syncthreads();
    if (tid == 0) {
        float bs = 0.f;
        #pragma unroll
        for (int i = 0; i < 8; ++i) bs += wsums[i];
        atomicAdd(&out[b], bs * (1.0f / 119070.0f));   // /(15*63*63)/2
    }
}

extern "C" void kernel_launch(void* const* d_in, const int* in_sizes, int n_in,
                              void* d_out, int out_size, void* d_ws, size_t ws_size,
                              hipStream_t stream) {
    const float* x      = (const float*)d_in[0];
    const float* conv_w = (const float*)d_in[1];
    const float* conv_b = (const float*)d_in[2];
    const float* bias   = (const float*)d_in[3];
    float* out = (float*)d_out;
    short* wtab = (short*)d_ws;   // 9216 B

    init_kernel<<<1, 576, 0, stream>>>(conv_w, bias, wtab, out);
    dim3 grid(63, 32);  // (hp, b) pre-swizzle
    fused_conv_pool_reduce<<<grid, 512, 0, stream>>>(x, wtab, conv_b, out);
}